// Round 10
// baseline (543.221 us; speedup 1.0000x reference)
//
#include <hip/hip_runtime.h>
#include <hip/hip_bf16.h>

typedef __attribute__((ext_vector_type(8))) short short8;
typedef __attribute__((ext_vector_type(4))) float f32x4;
typedef __attribute__((ext_vector_type(16))) float f32x16;

#define LOG2E 1.44269504088896340736f

// ---------------- fused f32 -> bf16 conversions ----------------
__global__ __launch_bounds__(256) void k_cvtX(const float* __restrict__ q_in,
                                              const float* __restrict__ kv_in,
                                              __hip_bfloat16* __restrict__ Xq) {
  int i = blockIdx.x * blockDim.x + threadIdx.x;
  const int stride = gridDim.x * blockDim.x;
  for (; i < 4194304; i += stride) {
    const float4 v = (i < 2097152) ? reinterpret_cast<const float4*>(q_in)[i]
                                   : reinterpret_cast<const float4*>(kv_in)[i - 2097152];
    union { __hip_bfloat16 h[4]; short4 s; } p;
    p.h[0] = __float2bfloat16(v.x);
    p.h[1] = __float2bfloat16(v.y);
    p.h[2] = __float2bfloat16(v.z);
    p.h[3] = __float2bfloat16(v.w);
    reinterpret_cast<short4*>(Xq)[i] = p.s;
  }
}

__global__ __launch_bounds__(256) void k_cvtW(const float* __restrict__ Wq,
                                              const float* __restrict__ Wk,
                                              const float* __restrict__ Wv,
                                              const float* __restrict__ Wo,
                                              __hip_bfloat16* __restrict__ Wqkv,
                                              __hip_bfloat16* __restrict__ Wob) {
  int i = blockIdx.x * blockDim.x + threadIdx.x;
  const int stride = gridDim.x * blockDim.x;
  for (; i < 1048576; i += stride) {
    float4 v;
    short4* dst;
    if (i < 786432) {
      const float4* src = (i < 262144) ? reinterpret_cast<const float4*>(Wq)
                         : (i < 524288) ? reinterpret_cast<const float4*>(Wk)
                                        : reinterpret_cast<const float4*>(Wv);
      v = src[i & 262143];
      dst = reinterpret_cast<short4*>(Wqkv) + i;
    } else {
      v = reinterpret_cast<const float4*>(Wo)[i - 786432];
      dst = reinterpret_cast<short4*>(Wob) + (i - 786432);
    }
    union { __hip_bfloat16 h[4]; short4 s; } p;
    p.h[0] = __float2bfloat16(v.x);
    p.h[1] = __float2bfloat16(v.y);
    p.h[2] = __float2bfloat16(v.z);
    p.h[3] = __float2bfloat16(v.w);
    *dst = p.s;
  }
}

// ---------------- async global->LDS helper ----------------
__device__ __forceinline__ void gload_lds16(const __hip_bfloat16* g, __hip_bfloat16* l) {
  __builtin_amdgcn_global_load_lds(
      (const __attribute__((address_space(1))) unsigned int*)g,
      (__attribute__((address_space(3))) unsigned int*)l, 16, 0, 0);
}

__device__ __forceinline__ unsigned pk_bf16(float a, float b) {
  union { __hip_bfloat16 h; unsigned short u; } x, y;
  x.h = __float2bfloat16(a);
  y.h = __float2bfloat16(b);
  return (unsigned)x.u | ((unsigned)y.u << 16);
}

// v_permlane32_swap_b32 with correct dataflow (two distinct results).
__device__ __forceinline__ void plswap2(unsigned a, unsigned b, unsigned& x, unsigned& y) {
#if __has_builtin(__builtin_amdgcn_permlane32_swap)
  auto r = __builtin_amdgcn_permlane32_swap(a, b, false, false);
  x = r[0];
  y = r[1];
#else
  unsigned d, s;
  asm volatile("v_mov_b32 %0, %2\n\tv_mov_b32 %1, %3\n\tv_permlane32_swap_b32 %0, %1"
               : "=&v"(d), "=&v"(s)
               : "v"(a), "v"(b));
  x = d;
  y = s;
#endif
}

// ---------------- GEMM: C[M,N] = A[M,K] @ W[N,K]^T + bias ----------------
// 4-buffer pipeline, one raw barrier per K-step, counted vmcnt (verified R6).
// Q scale folds LOG2E so attention softmax can use exp2 directly.
template <int NB, int OUTMODE>
__global__ __launch_bounds__(256, 4) void k_gemm(
    const __hip_bfloat16* __restrict__ Aq, const __hip_bfloat16* __restrict__ Akv,
    const __hip_bfloat16* __restrict__ Wt,
    const float* __restrict__ b0p, const float* __restrict__ b1p, const float* __restrict__ b2p,
    __hip_bfloat16* __restrict__ Obf, float* __restrict__ Of) {
  const int K = 1024;
  __shared__ __hip_bfloat16 As[4][4096];
  __shared__ __hip_bfloat16 Bs[4][4096];
  const int tid = threadIdx.x;
  const int lane = tid & 63;
  const int w = tid >> 6;
  const int wr = w >> 1, wc = w & 1;
  const int lg = lane >> 4, lr = lane & 15;

  const int bid = blockIdx.x;
  const int xcd = bid & 7, idx = bid >> 3;
  const int m0 = (xcd * 8 + idx / NB) * 128;
  const int n0 = (idx % NB) * 128;

  const int proj = (OUTMODE == 0) ? (n0 >> 10) : 0;
  const __hip_bfloat16* A = (OUTMODE == 0) ? (proj == 0 ? Aq : Akv) : Aq;

  const f32x4 fzero = {0.f, 0.f, 0.f, 0.f};
  f32x4 acc[4][4];
#pragma unroll
  for (int i = 0; i < 4; i++)
#pragma unroll
    for (int j = 0; j < 4; j++) acc[i][j] = fzero;

  const int c0 = w * 2;
  const int srow = lane >> 2;
  const int scol = (lane & 3) * 8;

  auto STAGE = [&](int kt, int buf) {
    const int k0 = kt * 32;
#pragma unroll
    for (int i = 0; i < 2; i++) {
      const int c = c0 + i;
      const int row = c * 16 + srow;
      gload_lds16(A + (size_t)(m0 + row) * K + k0 + scol, As[buf] + c * 512);
      gload_lds16(Wt + (size_t)(n0 + row) * K + k0 + scol, Bs[buf] + c * 512);
    }
  };

  STAGE(0, 0);
  STAGE(1, 1);

  for (int kt = 0; kt < 32; ++kt) {
    if (kt + 2 < 32) {
      STAGE(kt + 2, (kt + 2) & 3);
      asm volatile("s_waitcnt vmcnt(8)" ::: "memory");
    } else if (kt + 1 < 32) {
      asm volatile("s_waitcnt vmcnt(4)" ::: "memory");
    } else {
      asm volatile("s_waitcnt vmcnt(0)" ::: "memory");
    }
    __builtin_amdgcn_s_barrier();

    const int bc = kt & 3;
    short8 af[4], bfr[4];
#pragma unroll
    for (int mi = 0; mi < 4; mi++)
      af[mi] = *(const short8*)(As[bc] + (wr * 64 + mi * 16 + lr) * 32 + lg * 8);
#pragma unroll
    for (int ni = 0; ni < 4; ni++)
      bfr[ni] = *(const short8*)(Bs[bc] + (wc * 64 + ni * 16 + lr) * 32 + lg * 8);
#pragma unroll
    for (int mi = 0; mi < 4; mi++)
#pragma unroll
      for (int ni = 0; ni < 4; ni++)
        acc[mi][ni] = __builtin_amdgcn_mfma_f32_16x16x32_bf16(af[mi], bfr[ni], acc[mi][ni], 0, 0, 0);
  }

  // Q gets 0.125 * LOG2E so scores arrive in exp2 domain.
  const float scale = (OUTMODE == 0 && proj == 0) ? (0.125f * LOG2E) : 1.0f;
  const float* bias = (OUTMODE == 0) ? (proj == 0 ? b0p : (proj == 1 ? b1p : b2p)) : b0p;
  __hip_bfloat16* Ob = (OUTMODE == 0) ? (Obf + (size_t)proj * 8388608) : nullptr;

#pragma unroll
  for (int mi = 0; mi < 4; mi++) {
#pragma unroll
    for (int ni = 0; ni < 4; ni++) {
      const int n = n0 + wc * 64 + ni * 16 + lr;
      const float bn = bias[n & 1023];
#pragma unroll
      for (int r = 0; r < 4; r++) {
        const int m = m0 + wr * 64 + mi * 16 + lg * 4 + r;
        const float v = (acc[mi][ni][r] + bn) * scale;
        if (OUTMODE == 0) {
          const int b = m >> 11, t = m & 2047;
          const int h = (n >> 6) & 15, d = n & 63;
          Ob[(((size_t)(b * 16 + h)) * 2048 + t) * 64 + d] = __float2bfloat16(v);
        } else {
          Of[(size_t)m * 1024 + n] = v;
        }
      }
    }
  }
}

// ---------------- V transpose: [BH, T, 64] -> [BH, 64, T] ----------------
__global__ __launch_bounds__(256) void k_transpose(const __hip_bfloat16* __restrict__ V,
                                                   __hip_bfloat16* __restrict__ Vt) {
  __shared__ __hip_bfloat16 tile[64][72];
  const int bh = blockIdx.y;
  const int t0 = blockIdx.x * 64;
  const int tid = threadIdx.x;
#pragma unroll
  for (int it = 0; it < 2; ++it) {
    const int r = it * 32 + (tid >> 3);
    const int c = (tid & 7) * 8;
    short8 v = *(const short8*)(V + ((size_t)bh * 2048 + t0 + r) * 64 + c);
    *(short8*)(&tile[r][c]) = v;
  }
  __syncthreads();
#pragma unroll
  for (int it = 0; it < 2; ++it) {
    const int d = it * 32 + (tid >> 3);
    const int tt = (tid & 7) * 8;
    __hip_bfloat16 tmp[8];
#pragma unroll
    for (int j = 0; j < 8; j++) tmp[j] = tile[tt + j][d];
    *(short8*)(Vt + ((size_t)bh * 64 + d) * 2048 + t0 + tt) = *(short8*)tmp;
  }
}

// ---------------- banded flash attention: 8-wave, QBLK=256, no-max softmax ----------------
// R9-verified 3-buffer single-barrier pipeline at 3 blocks/CU x 8 waves = 24 waves/CU.
// iter t: STAGE(t+1)->buf (t+1)%3; vmcnt(2); s_barrier; compute buf t%3.
__global__ __launch_bounds__(512, 6) void k_attn6(const __hip_bfloat16* __restrict__ Qm,
                                                  const __hip_bfloat16* __restrict__ Km,
                                                  const __hip_bfloat16* __restrict__ Vt,
                                                  __hip_bfloat16* __restrict__ O,
                                                  const int* __restrict__ la_ptr) {
  const int T = 2048;
  __shared__ __hip_bfloat16 Ks[3][4096];  // [key][d], 64x64, XOR-swizzled cols
  __shared__ __hip_bfloat16 Vs[3][4096];  // [d][key]
  const int tid = threadIdx.x;
  const int lane = tid & 63;
  const int w = tid >> 6;          // 0..7
  const int hi = lane >> 5;
  const int l31 = lane & 31;

  // complementary XCD remap, bijective on 512 blocks, longest q-blocks first:
  // XCD x gets qblk {7-x (bh 0..31), x (bh 32..63)} -> tile sums {38,40,...,38}
  const int l = blockIdx.y * 8 + blockIdx.x;
  const int half = l >> 8;
  const int u = l & 255;
  const int xi = u & 7;
  const int yi = u >> 3;
  const int qblk = half ? xi : (7 - xi);
  const int bh = yi + (half << 5);

  const int q0 = qblk * 256;
  const int la = *la_ptr;
  const int qw = q0 + w * 32;
  const int q = qw + l31;

  // Q B-fragments: B[n=q, k=ks*16+hi*8+j]
  short8 qf[4];
  {
    const __hip_bfloat16* qrow = Qm + ((size_t)bh * T + q) * 64;
#pragma unroll
    for (int ks = 0; ks < 4; ks++) qf[ks] = *(const short8*)(qrow + ks * 16 + hi * 8);
  }

  f32x16 acc0, acc1;
#pragma unroll
  for (int r = 0; r < 16; r++) { acc0[r] = 0.f; acc1[r] = 0.f; }
  float lsum = 0.f;

  const int kend_w = min(T, qw + 32 + la);
  const int kend_b = min(T, q0 + 256 + la);
  const int ntiles = (kend_b + 63) >> 6;

  // staging: 512 threads x 16B = one 8KB (64x64) tile per call
  const int srow = tid >> 3;               // 0..63
  const int sc16 = (tid & 7) ^ (srow & 7);
  const __hip_bfloat16* Kg = Km + (size_t)bh * T * 64 + (size_t)srow * 64 + sc16 * 8;
  const __hip_bfloat16* Vg = Vt + (size_t)bh * 64 * T + (size_t)srow * T + sc16 * 8;
  const int kswz = l31 & 7;

  auto STAGEKV = [&](int t, int buf) {
    gload_lds16(Kg + (size_t)(t << 6) * 64, Ks[buf] + w * 512);
    gload_lds16(Vg + (t << 6), Vs[buf] + w * 512);
  };

  auto QK = [&](const __hip_bfloat16* Ksc, int kt2) {
    const int krow = kt2 * 32 + l31;
    f32x16 s;
#pragma unroll
    for (int r = 0; r < 16; r++) s[r] = 0.f;
    __builtin_amdgcn_s_setprio(1);
#pragma unroll
    for (int ks = 0; ks < 4; ks++) {
      short8 kf = *(const short8*)((const char*)Ksc + krow * 128 +
                                   ((((ks << 1) | hi)) ^ kswz) * 16);
      s = __builtin_amdgcn_mfma_f32_32x32x16_bf16(kf, qf[ks], s, 0, 0, 0);
    }
    __builtin_amdgcn_s_setprio(0);
    return s;
  };

  auto SMPV = [&](f32x16& s, int kb32, int kt2, const __hip_bfloat16* Vsc) {
    if (kb32 + 31 > qw + la) {
      const int thr = q + la - kb32;
#pragma unroll
      for (int r = 0; r < 16; r++) {
        const int crow = (r & 3) + ((r >> 2) << 3) + (hi << 2);
        if (crow > thr) s[r] = -1e30f;
      }
    }
    // no-max softmax: P = exp2(S), exact by shift-invariance (|S| small)
    float e[16];
#pragma unroll
    for (int i = 0; i < 16; i++) e[i] = exp2f(s[i]);
    float p01 = (e[0] + e[1]) + (e[2] + e[3]);
    float p23 = (e[4] + e[5]) + (e[6] + e[7]);
    float p45 = (e[8] + e[9]) + (e[10] + e[11]);
    float p67 = (e[12] + e[13]) + (e[14] + e[15]);
    lsum += (p01 + p23) + (p45 + p67);
    unsigned W[8];
#pragma unroll
    for (int i = 0; i < 8; i++) W[i] = pk_bf16(e[2 * i], e[2 * i + 1]);

    int4 A0, A1;
    {
      unsigned x0, z0, y0, w0, x1, z1, y1, w1;
      plswap2(W[0], W[2], x0, z0);
      plswap2(W[1], W[3], y0, w0);
      plswap2(W[4], W[6], x1, z1);
      plswap2(W[5], W[7], y1, w1);
      A0.x = (int)x0; A0.y = (int)y0; A0.z = (int)z0; A0.w = (int)w0;
      A1.x = (int)x1; A1.y = (int)y1; A1.z = (int)z1; A1.w = (int)w1;
    }

    __builtin_amdgcn_s_setprio(1);
#pragma unroll
    for (int ks2 = 0; ks2 < 2; ks2++) {
      union { int4 i; short8 s8; } pa;
      pa.i = ks2 ? A1 : A0;
      const int ksg = kt2 * 2 + ks2;
      const int col16 = ((ksg << 1) | hi);
      short8 vf0 = *(const short8*)((const char*)Vsc + l31 * 128 + ((col16 ^ kswz)) * 16);
      short8 vf1 = *(const short8*)((const char*)Vsc + (32 + l31) * 128 + ((col16 ^ kswz)) * 16);
      acc0 = __builtin_amdgcn_mfma_f32_32x32x16_bf16(vf0, pa.s8, acc0, 0, 0, 0);
      acc1 = __builtin_amdgcn_mfma_f32_32x32x16_bf16(vf1, pa.s8, acc1, 0, 0, 0);
    }
    __builtin_amdgcn_s_setprio(0);
  };

  // prologue: stage tile 0 into buf 0
  STAGEKV(0, 0);

  int cur = 0, nxt = 1;
  for (int kt = 0; kt < ntiles; ++kt) {
    const int kbase = kt << 6;
    if (kt + 1 < ntiles) {
      STAGEKV(kt + 1, nxt);
      asm volatile("s_waitcnt vmcnt(2)" ::: "memory");
    } else {
      asm volatile("s_waitcnt vmcnt(0)" ::: "memory");
    }
    __builtin_amdgcn_s_barrier();

    if (kbase < kend_w) {
      const __hip_bfloat16* Ksc = Ks[cur];
      const __hip_bfloat16* Vsc = Vs[cur];
      const bool d1 = (kbase + 32) < kend_w;
      f32x16 sA = QK(Ksc, 0);
      f32x16 sB;
      if (d1) sB = QK(Ksc, 1);
      SMPV(sA, kbase, 0, Vsc);
      if (d1) SMPV(sB, kbase + 32, 1, Vsc);
    }
    cur = nxt;
    nxt = (nxt == 2) ? 0 : nxt + 1;
  }

  {
    unsigned r0, r1;
    plswap2(__float_as_uint(lsum), __float_as_uint(lsum), r0, r1);
    lsum = __uint_as_float(r0) + __uint_as_float(r1);
  }
  const float rinv = 1.f / lsum;
  const int b = bh >> 4, h = bh & 15;
  __hip_bfloat16* orow = O + ((size_t)(b * T + q)) * 1024 + h * 64;
#pragma unroll
  for (int rq = 0; rq < 4; rq++) {
    const int d0 = rq * 8 + hi * 4;
    union { __hip_bfloat16 h4[4]; short4 s4; } o;
#pragma unroll
    for (int j = 0; j < 4; j++) o.h4[j] = __float2bfloat16(acc0[rq * 4 + j] * rinv);
    *(short4*)(orow + d0) = o.s4;
  }
#pragma unroll
  for (int rq = 0; rq < 4; rq++) {
    const int d0 = rq * 8 + hi * 4 + 32;
    union { __hip_bfloat16 h4[4]; short4 s4; } o;
#pragma unroll
    for (int j = 0; j < 4; j++) o.h4[j] = __float2bfloat16(acc1[rq * 4 + j] * rinv);
    *(short4*)(orow + d0) = o.s4;
  }
}

// ---------------- launch ----------------
extern "C" void kernel_launch(void* const* d_in, const int* in_sizes, int n_in,
                              void* d_out, int out_size, void* d_ws, size_t ws_size,
                              hipStream_t stream) {
  const float* q_in = (const float*)d_in[0];
  const float* kv_in = (const float*)d_in[1];
  const float* Wq = (const float*)d_in[2];
  const float* bq = (const float*)d_in[3];
  const float* Wk = (const float*)d_in[4];
  const float* bk = (const float*)d_in[5];
  const float* Wv = (const float*)d_in[6];
  const float* bv = (const float*)d_in[7];
  const float* Wo = (const float*)d_in[8];
  const float* bo = (const float*)d_in[9];
  const int* la = (const int*)d_in[10];

  char* ws = (char*)d_ws;
  const size_t SZX = (size_t)8192 * 1024 * 2;  // 16 MiB
  const size_t SZW = (size_t)1024 * 1024 * 2;  // 2 MiB
  __hip_bfloat16* Xq = (__hip_bfloat16*)(ws);                 // +Xkv contiguous
  __hip_bfloat16* Xkv = (__hip_bfloat16*)(ws + SZX);
  __hip_bfloat16* Wqkv = (__hip_bfloat16*)(ws + 2 * SZX);     // 6 MiB
  __hip_bfloat16* Wob = (__hip_bfloat16*)(ws + 2 * SZX + 3 * SZW);
  __hip_bfloat16* Qb = (__hip_bfloat16*)(ws + 2 * SZX + 4 * SZW);  // Qb|Kb|Vb contiguous
  __hip_bfloat16* Kb = (__hip_bfloat16*)(ws + 3 * SZX + 4 * SZW);
  __hip_bfloat16* Vb = (__hip_bfloat16*)(ws + 4 * SZX + 4 * SZW);
  __hip_bfloat16* Vtb = (__hip_bfloat16*)(ws);        // alias Xq (free after QKV GEMM)
  __hip_bfloat16* AOb = (__hip_bfloat16*)(ws + SZX);  // alias Xkv (free after QKV GEMM)

  k_cvtX<<<4096, 256, 0, stream>>>(q_in, kv_in, Xq);
  k_cvtW<<<2048, 256, 0, stream>>>(Wq, Wk, Wv, Wo, Wqkv, Wob);

  // fused QKV projection: 64 m-blocks x 24 n-blocks
  k_gemm<24, 0><<<1536, 256, 0, stream>>>(Xq, Xkv, Wqkv, bq, bk, bv, Qb, nullptr);
  k_transpose<<<dim3(32, 64), 256, 0, stream>>>(Vb, Vtb);
  k_attn6<<<dim3(8, 64), 512, 0, stream>>>(Qb, Kb, Vtb, AOb, la);
  // output projection: 64 x 8 blocks, f32 out
  k_gemm<8, 1><<<512, 256, 0, stream>>>(AOb, AOb, Wob, bo, bo, bo, nullptr, (float*)d_out);

  (void)Kb;
}

// Round 11
// 222.724 us; speedup vs baseline: 2.4390x; 2.4390x over previous
//
#include <hip/hip_runtime.h>
#include <hip/hip_bf16.h>

typedef __attribute__((ext_vector_type(8))) short short8;
typedef __attribute__((ext_vector_type(4))) float f32x4;
typedef __attribute__((ext_vector_type(16))) float f32x16;

#define LOG2E 1.44269504088896340736f

// ---------------- fused f32 -> bf16 conversions ----------------
__global__ __launch_bounds__(256) void k_cvtX(const float* __restrict__ q_in,
                                              const float* __restrict__ kv_in,
                                              __hip_bfloat16* __restrict__ Xq) {
  int i = blockIdx.x * blockDim.x + threadIdx.x;
  const int stride = gridDim.x * blockDim.x;
  for (; i < 4194304; i += stride) {
    const float4 v = (i < 2097152) ? reinterpret_cast<const float4*>(q_in)[i]
                                   : reinterpret_cast<const float4*>(kv_in)[i - 2097152];
    union { __hip_bfloat16 h[4]; short4 s; } p;
    p.h[0] = __float2bfloat16(v.x);
    p.h[1] = __float2bfloat16(v.y);
    p.h[2] = __float2bfloat16(v.z);
    p.h[3] = __float2bfloat16(v.w);
    reinterpret_cast<short4*>(Xq)[i] = p.s;
  }
}

__global__ __launch_bounds__(256) void k_cvtW(const float* __restrict__ Wq,
                                              const float* __restrict__ Wk,
                                              const float* __restrict__ Wv,
                                              const float* __restrict__ Wo,
                                              __hip_bfloat16* __restrict__ Wqkv,
                                              __hip_bfloat16* __restrict__ Wob) {
  int i = blockIdx.x * blockDim.x + threadIdx.x;
  const int stride = gridDim.x * blockDim.x;
  for (; i < 1048576; i += stride) {
    float4 v;
    short4* dst;
    if (i < 786432) {
      const float4* src = (i < 262144) ? reinterpret_cast<const float4*>(Wq)
                         : (i < 524288) ? reinterpret_cast<const float4*>(Wk)
                                        : reinterpret_cast<const float4*>(Wv);
      v = src[i & 262143];
      dst = reinterpret_cast<short4*>(Wqkv) + i;
    } else {
      v = reinterpret_cast<const float4*>(Wo)[i - 786432];
      dst = reinterpret_cast<short4*>(Wob) + (i - 786432);
    }
    union { __hip_bfloat16 h[4]; short4 s; } p;
    p.h[0] = __float2bfloat16(v.x);
    p.h[1] = __float2bfloat16(v.y);
    p.h[2] = __float2bfloat16(v.z);
    p.h[3] = __float2bfloat16(v.w);
    *dst = p.s;
  }
}

// ---------------- async global->LDS helper ----------------
__device__ __forceinline__ void gload_lds16(const __hip_bfloat16* g, __hip_bfloat16* l) {
  __builtin_amdgcn_global_load_lds(
      (const __attribute__((address_space(1))) unsigned int*)g,
      (__attribute__((address_space(3))) unsigned int*)l, 16, 0, 0);
}

__device__ __forceinline__ unsigned pk_bf16(float a, float b) {
  union { __hip_bfloat16 h; unsigned short u; } x, y;
  x.h = __float2bfloat16(a);
  y.h = __float2bfloat16(b);
  return (unsigned)x.u | ((unsigned)y.u << 16);
}

// v_permlane32_swap_b32 with correct dataflow (two distinct results).
__device__ __forceinline__ void plswap2(unsigned a, unsigned b, unsigned& x, unsigned& y) {
#if __has_builtin(__builtin_amdgcn_permlane32_swap)
  auto r = __builtin_amdgcn_permlane32_swap(a, b, false, false);
  x = r[0];
  y = r[1];
#else
  unsigned d, s;
  asm volatile("v_mov_b32 %0, %2\n\tv_mov_b32 %1, %3\n\tv_permlane32_swap_b32 %0, %1"
               : "=&v"(d), "=&v"(s)
               : "v"(a), "v"(b));
  x = d;
  y = s;
#endif
}

// ---------------- GEMM: C[M,N] = A[M,K] @ W[N,K]^T + bias ----------------
// 4-buffer pipeline, one raw barrier per K-step, counted vmcnt (verified R6).
// Q scale folds LOG2E so attention softmax can use exp2 directly.
template <int NB, int OUTMODE>
__global__ __launch_bounds__(256, 4) void k_gemm(
    const __hip_bfloat16* __restrict__ Aq, const __hip_bfloat16* __restrict__ Akv,
    const __hip_bfloat16* __restrict__ Wt,
    const float* __restrict__ b0p, const float* __restrict__ b1p, const float* __restrict__ b2p,
    __hip_bfloat16* __restrict__ Obf, float* __restrict__ Of) {
  const int K = 1024;
  __shared__ __hip_bfloat16 As[4][4096];
  __shared__ __hip_bfloat16 Bs[4][4096];
  const int tid = threadIdx.x;
  const int lane = tid & 63;
  const int w = tid >> 6;
  const int wr = w >> 1, wc = w & 1;
  const int lg = lane >> 4, lr = lane & 15;

  const int bid = blockIdx.x;
  const int xcd = bid & 7, idx = bid >> 3;
  const int m0 = (xcd * 8 + idx / NB) * 128;
  const int n0 = (idx % NB) * 128;

  const int proj = (OUTMODE == 0) ? (n0 >> 10) : 0;
  const __hip_bfloat16* A = (OUTMODE == 0) ? (proj == 0 ? Aq : Akv) : Aq;

  const f32x4 fzero = {0.f, 0.f, 0.f, 0.f};
  f32x4 acc[4][4];
#pragma unroll
  for (int i = 0; i < 4; i++)
#pragma unroll
    for (int j = 0; j < 4; j++) acc[i][j] = fzero;

  const int c0 = w * 2;
  const int srow = lane >> 2;
  const int scol = (lane & 3) * 8;

  auto STAGE = [&](int kt, int buf) {
    const int k0 = kt * 32;
#pragma unroll
    for (int i = 0; i < 2; i++) {
      const int c = c0 + i;
      const int row = c * 16 + srow;
      gload_lds16(A + (size_t)(m0 + row) * K + k0 + scol, As[buf] + c * 512);
      gload_lds16(Wt + (size_t)(n0 + row) * K + k0 + scol, Bs[buf] + c * 512);
    }
  };

  STAGE(0, 0);
  STAGE(1, 1);

  for (int kt = 0; kt < 32; ++kt) {
    if (kt + 2 < 32) {
      STAGE(kt + 2, (kt + 2) & 3);
      asm volatile("s_waitcnt vmcnt(8)" ::: "memory");
    } else if (kt + 1 < 32) {
      asm volatile("s_waitcnt vmcnt(4)" ::: "memory");
    } else {
      asm volatile("s_waitcnt vmcnt(0)" ::: "memory");
    }
    __builtin_amdgcn_s_barrier();

    const int bc = kt & 3;
    short8 af[4], bfr[4];
#pragma unroll
    for (int mi = 0; mi < 4; mi++)
      af[mi] = *(const short8*)(As[bc] + (wr * 64 + mi * 16 + lr) * 32 + lg * 8);
#pragma unroll
    for (int ni = 0; ni < 4; ni++)
      bfr[ni] = *(const short8*)(Bs[bc] + (wc * 64 + ni * 16 + lr) * 32 + lg * 8);
#pragma unroll
    for (int mi = 0; mi < 4; mi++)
#pragma unroll
      for (int ni = 0; ni < 4; ni++)
        acc[mi][ni] = __builtin_amdgcn_mfma_f32_16x16x32_bf16(af[mi], bfr[ni], acc[mi][ni], 0, 0, 0);
  }

  // Q gets 0.125 * LOG2E so scores arrive in exp2 domain.
  const float scale = (OUTMODE == 0 && proj == 0) ? (0.125f * LOG2E) : 1.0f;
  const float* bias = (OUTMODE == 0) ? (proj == 0 ? b0p : (proj == 1 ? b1p : b2p)) : b0p;
  __hip_bfloat16* Ob = (OUTMODE == 0) ? (Obf + (size_t)proj * 8388608) : nullptr;

#pragma unroll
  for (int mi = 0; mi < 4; mi++) {
#pragma unroll
    for (int ni = 0; ni < 4; ni++) {
      const int n = n0 + wc * 64 + ni * 16 + lr;
      const float bn = bias[n & 1023];
#pragma unroll
      for (int r = 0; r < 4; r++) {
        const int m = m0 + wr * 64 + mi * 16 + lg * 4 + r;
        const float v = (acc[mi][ni][r] + bn) * scale;
        if (OUTMODE == 0) {
          const int b = m >> 11, t = m & 2047;
          const int h = (n >> 6) & 15, d = n & 63;
          Ob[(((size_t)(b * 16 + h)) * 2048 + t) * 64 + d] = __float2bfloat16(v);
        } else {
          Of[(size_t)m * 1024 + n] = v;
        }
      }
    }
  }
}

// ---------------- V transpose: [BH, T, 64] -> [BH, 64, T] ----------------
__global__ __launch_bounds__(256) void k_transpose(const __hip_bfloat16* __restrict__ V,
                                                   __hip_bfloat16* __restrict__ Vt) {
  __shared__ __hip_bfloat16 tile[64][72];
  const int bh = blockIdx.y;
  const int t0 = blockIdx.x * 64;
  const int tid = threadIdx.x;
#pragma unroll
  for (int it = 0; it < 2; ++it) {
    const int r = it * 32 + (tid >> 3);
    const int c = (tid & 7) * 8;
    short8 v = *(const short8*)(V + ((size_t)bh * 2048 + t0 + r) * 64 + c);
    *(short8*)(&tile[r][c]) = v;
  }
  __syncthreads();
#pragma unroll
  for (int it = 0; it < 2; ++it) {
    const int d = it * 32 + (tid >> 3);
    const int tt = (tid & 7) * 8;
    __hip_bfloat16 tmp[8];
#pragma unroll
    for (int j = 0; j < 8; j++) tmp[j] = tile[tt + j][d];
    *(short8*)(Vt + ((size_t)bh * 64 + d) * 2048 + t0 + tt) = *(short8*)tmp;
  }
}

// ---------------- banded flash attention: 8-wave, QBLK=256, no-max softmax ----------------
// R9-verified 3-buffer single-barrier pipeline. 8 waves/block; LDS (48KB) bounds
// occupancy at 3 blocks/CU = 6 waves/SIMD; launch_bounds kept LOOSE (min 2 waves/EU)
// so the register allocator is NOT constrained (R10's (512,6) forced 40 VGPR -> spills).
__global__ __launch_bounds__(512, 2) void k_attn6(const __hip_bfloat16* __restrict__ Qm,
                                                  const __hip_bfloat16* __restrict__ Km,
                                                  const __hip_bfloat16* __restrict__ Vt,
                                                  __hip_bfloat16* __restrict__ O,
                                                  const int* __restrict__ la_ptr) {
  const int T = 2048;
  __shared__ __hip_bfloat16 Ks[3][4096];  // [key][d], 64x64, XOR-swizzled cols
  __shared__ __hip_bfloat16 Vs[3][4096];  // [d][key]
  const int tid = threadIdx.x;
  const int lane = tid & 63;
  const int w = tid >> 6;          // 0..7
  const int hi = lane >> 5;
  const int l31 = lane & 31;

  // complementary XCD remap, bijective on 512 blocks, longest q-blocks first:
  // XCD x gets qblk {7-x (bh 0..31), x (bh 32..63)} -> tile sums {38,40,...,38}
  const int l = blockIdx.y * 8 + blockIdx.x;
  const int half = l >> 8;
  const int u = l & 255;
  const int xi = u & 7;
  const int yi = u >> 3;
  const int qblk = half ? xi : (7 - xi);
  const int bh = yi + (half << 5);

  const int q0 = qblk * 256;
  const int la = *la_ptr;
  const int qw = q0 + w * 32;
  const int q = qw + l31;

  // Q B-fragments: B[n=q, k=ks*16+hi*8+j]
  short8 qf[4];
  {
    const __hip_bfloat16* qrow = Qm + ((size_t)bh * T + q) * 64;
#pragma unroll
    for (int ks = 0; ks < 4; ks++) qf[ks] = *(const short8*)(qrow + ks * 16 + hi * 8);
  }

  f32x16 acc0, acc1;
#pragma unroll
  for (int r = 0; r < 16; r++) { acc0[r] = 0.f; acc1[r] = 0.f; }
  float lsum = 0.f;

  const int kend_w = min(T, qw + 32 + la);
  const int kend_b = min(T, q0 + 256 + la);
  const int ntiles = (kend_b + 63) >> 6;

  // staging: 512 threads x 16B = one 8KB (64x64) tile per call
  const int srow = tid >> 3;               // 0..63
  const int sc16 = (tid & 7) ^ (srow & 7);
  const __hip_bfloat16* Kg = Km + (size_t)bh * T * 64 + (size_t)srow * 64 + sc16 * 8;
  const __hip_bfloat16* Vg = Vt + (size_t)bh * 64 * T + (size_t)srow * T + sc16 * 8;
  const int kswz = l31 & 7;

  auto STAGEKV = [&](int t, int buf) {
    gload_lds16(Kg + (size_t)(t << 6) * 64, Ks[buf] + w * 512);
    gload_lds16(Vg + (t << 6), Vs[buf] + w * 512);
  };

  auto QK = [&](const __hip_bfloat16* Ksc, int kt2) {
    const int krow = kt2 * 32 + l31;
    f32x16 s;
#pragma unroll
    for (int r = 0; r < 16; r++) s[r] = 0.f;
    __builtin_amdgcn_s_setprio(1);
#pragma unroll
    for (int ks = 0; ks < 4; ks++) {
      short8 kf = *(const short8*)((const char*)Ksc + krow * 128 +
                                   ((((ks << 1) | hi)) ^ kswz) * 16);
      s = __builtin_amdgcn_mfma_f32_32x32x16_bf16(kf, qf[ks], s, 0, 0, 0);
    }
    __builtin_amdgcn_s_setprio(0);
    return s;
  };

  auto SMPV = [&](f32x16& s, int kb32, int kt2, const __hip_bfloat16* Vsc) {
    if (kb32 + 31 > qw + la) {
      const int thr = q + la - kb32;
#pragma unroll
      for (int r = 0; r < 16; r++) {
        const int crow = (r & 3) + ((r >> 2) << 3) + (hi << 2);
        if (crow > thr) s[r] = -1e30f;
      }
    }
    // no-max softmax: P = exp2(S), exact by shift-invariance (|S| small)
    float e[16];
#pragma unroll
    for (int i = 0; i < 16; i++) e[i] = exp2f(s[i]);
    float p01 = (e[0] + e[1]) + (e[2] + e[3]);
    float p23 = (e[4] + e[5]) + (e[6] + e[7]);
    float p45 = (e[8] + e[9]) + (e[10] + e[11]);
    float p67 = (e[12] + e[13]) + (e[14] + e[15]);
    lsum += (p01 + p23) + (p45 + p67);
    unsigned W[8];
#pragma unroll
    for (int i = 0; i < 8; i++) W[i] = pk_bf16(e[2 * i], e[2 * i + 1]);

    int4 A0, A1;
    {
      unsigned x0, z0, y0, w0, x1, z1, y1, w1;
      plswap2(W[0], W[2], x0, z0);
      plswap2(W[1], W[3], y0, w0);
      plswap2(W[4], W[6], x1, z1);
      plswap2(W[5], W[7], y1, w1);
      A0.x = (int)x0; A0.y = (int)y0; A0.z = (int)z0; A0.w = (int)w0;
      A1.x = (int)x1; A1.y = (int)y1; A1.z = (int)z1; A1.w = (int)w1;
    }

    __builtin_amdgcn_s_setprio(1);
#pragma unroll
    for (int ks2 = 0; ks2 < 2; ks2++) {
      union { int4 i; short8 s8; } pa;
      pa.i = ks2 ? A1 : A0;
      const int ksg = kt2 * 2 + ks2;
      const int col16 = ((ksg << 1) | hi);
      short8 vf0 = *(const short8*)((const char*)Vsc + l31 * 128 + ((col16 ^ kswz)) * 16);
      short8 vf1 = *(const short8*)((const char*)Vsc + (32 + l31) * 128 + ((col16 ^ kswz)) * 16);
      acc0 = __builtin_amdgcn_mfma_f32_32x32x16_bf16(vf0, pa.s8, acc0, 0, 0, 0);
      acc1 = __builtin_amdgcn_mfma_f32_32x32x16_bf16(vf1, pa.s8, acc1, 0, 0, 0);
    }
    __builtin_amdgcn_s_setprio(0);
  };

  // prologue: stage tile 0 into buf 0
  STAGEKV(0, 0);

  int cur = 0, nxt = 1;
  for (int kt = 0; kt < ntiles; ++kt) {
    const int kbase = kt << 6;
    if (kt + 1 < ntiles) {
      STAGEKV(kt + 1, nxt);
      asm volatile("s_waitcnt vmcnt(2)" ::: "memory");
    } else {
      asm volatile("s_waitcnt vmcnt(0)" ::: "memory");
    }
    __builtin_amdgcn_s_barrier();

    if (kbase < kend_w) {
      const __hip_bfloat16* Ksc = Ks[cur];
      const __hip_bfloat16* Vsc = Vs[cur];
      const bool d1 = (kbase + 32) < kend_w;
      f32x16 sA = QK(Ksc, 0);
      f32x16 sB;
      if (d1) sB = QK(Ksc, 1);
      SMPV(sA, kbase, 0, Vsc);
      if (d1) SMPV(sB, kbase + 32, 1, Vsc);
    }
    cur = nxt;
    nxt = (nxt == 2) ? 0 : nxt + 1;
  }

  {
    unsigned r0, r1;
    plswap2(__float_as_uint(lsum), __float_as_uint(lsum), r0, r1);
    lsum = __uint_as_float(r0) + __uint_as_float(r1);
  }
  const float rinv = 1.f / lsum;
  const int b = bh >> 4, h = bh & 15;
  __hip_bfloat16* orow = O + ((size_t)(b * T + q)) * 1024 + h * 64;
#pragma unroll
  for (int rq = 0; rq < 4; rq++) {
    const int d0 = rq * 8 + hi * 4;
    union { __hip_bfloat16 h4[4]; short4 s4; } o;
#pragma unroll
    for (int j = 0; j < 4; j++) o.h4[j] = __float2bfloat16(acc0[rq * 4 + j] * rinv);
    *(short4*)(orow + d0) = o.s4;
  }
#pragma unroll
  for (int rq = 0; rq < 4; rq++) {
    const int d0 = rq * 8 + hi * 4 + 32;
    union { __hip_bfloat16 h4[4]; short4 s4; } o;
#pragma unroll
    for (int j = 0; j < 4; j++) o.h4[j] = __float2bfloat16(acc1[rq * 4 + j] * rinv);
    *(short4*)(orow + d0) = o.s4;
  }
}

// ---------------- launch ----------------
extern "C" void kernel_launch(void* const* d_in, const int* in_sizes, int n_in,
                              void* d_out, int out_size, void* d_ws, size_t ws_size,
                              hipStream_t stream) {
  const float* q_in = (const float*)d_in[0];
  const float* kv_in = (const float*)d_in[1];
  const float* Wq = (const float*)d_in[2];
  const float* bq = (const float*)d_in[3];
  const float* Wk = (const float*)d_in[4];
  const float* bk = (const float*)d_in[5];
  const float* Wv = (const float*)d_in[6];
  const float* bv = (const float*)d_in[7];
  const float* Wo = (const float*)d_in[8];
  const float* bo = (const float*)d_in[9];
  const int* la = (const int*)d_in[10];

  char* ws = (char*)d_ws;
  const size_t SZX = (size_t)8192 * 1024 * 2;  // 16 MiB
  const size_t SZW = (size_t)1024 * 1024 * 2;  // 2 MiB
  __hip_bfloat16* Xq = (__hip_bfloat16*)(ws);                 // +Xkv contiguous
  __hip_bfloat16* Xkv = (__hip_bfloat16*)(ws + SZX);
  __hip_bfloat16* Wqkv = (__hip_bfloat16*)(ws + 2 * SZX);     // 6 MiB
  __hip_bfloat16* Wob = (__hip_bfloat16*)(ws + 2 * SZX + 3 * SZW);
  __hip_bfloat16* Qb = (__hip_bfloat16*)(ws + 2 * SZX + 4 * SZW);  // Qb|Kb|Vb contiguous
  __hip_bfloat16* Kb = (__hip_bfloat16*)(ws + 3 * SZX + 4 * SZW);
  __hip_bfloat16* Vb = (__hip_bfloat16*)(ws + 4 * SZX + 4 * SZW);
  __hip_bfloat16* Vtb = (__hip_bfloat16*)(ws);        // alias Xq (free after QKV GEMM)
  __hip_bfloat16* AOb = (__hip_bfloat16*)(ws + SZX);  // alias Xkv (free after QKV GEMM)

  k_cvtX<<<4096, 256, 0, stream>>>(q_in, kv_in, Xq);
  k_cvtW<<<2048, 256, 0, stream>>>(Wq, Wk, Wv, Wo, Wqkv, Wob);

  // fused QKV projection: 64 m-blocks x 24 n-blocks
  k_gemm<24, 0><<<1536, 256, 0, stream>>>(Xq, Xkv, Wqkv, bq, bk, bv, Qb, nullptr);
  k_transpose<<<dim3(32, 64), 256, 0, stream>>>(Vb, Vtb);
  k_attn6<<<dim3(8, 64), 512, 0, stream>>>(Qb, Kb, Vtb, AOb, la);
  // output projection: 64 x 8 blocks, f32 out
  k_gemm<8, 1><<<512, 256, 0, stream>>>(AOb, AOb, Wob, bo, bo, bo, nullptr, (float*)d_out);

  (void)Kb;
}

// Round 12
// 217.153 us; speedup vs baseline: 2.5016x; 1.0257x over previous
//
#include <hip/hip_runtime.h>
#include <hip/hip_bf16.h>

typedef __attribute__((ext_vector_type(8))) short short8;
typedef __attribute__((ext_vector_type(4))) float f32x4;
typedef __attribute__((ext_vector_type(16))) float f32x16;

#define LOG2E 1.44269504088896340736f

// ---------------- fused f32 -> bf16 conversions ----------------
__global__ __launch_bounds__(256) void k_cvtX(const float* __restrict__ q_in,
                                              const float* __restrict__ kv_in,
                                              __hip_bfloat16* __restrict__ Xq) {
  int i = blockIdx.x * blockDim.x + threadIdx.x;
  const int stride = gridDim.x * blockDim.x;
  for (; i < 4194304; i += stride) {
    const float4 v = (i < 2097152) ? reinterpret_cast<const float4*>(q_in)[i]
                                   : reinterpret_cast<const float4*>(kv_in)[i - 2097152];
    union { __hip_bfloat16 h[4]; short4 s; } p;
    p.h[0] = __float2bfloat16(v.x);
    p.h[1] = __float2bfloat16(v.y);
    p.h[2] = __float2bfloat16(v.z);
    p.h[3] = __float2bfloat16(v.w);
    reinterpret_cast<short4*>(Xq)[i] = p.s;
  }
}

__global__ __launch_bounds__(256) void k_cvtW(const float* __restrict__ Wq,
                                              const float* __restrict__ Wk,
                                              const float* __restrict__ Wv,
                                              const float* __restrict__ Wo,
                                              __hip_bfloat16* __restrict__ Wqkv,
                                              __hip_bfloat16* __restrict__ Wob) {
  int i = blockIdx.x * blockDim.x + threadIdx.x;
  const int stride = gridDim.x * blockDim.x;
  for (; i < 1048576; i += stride) {
    float4 v;
    short4* dst;
    if (i < 786432) {
      const float4* src = (i < 262144) ? reinterpret_cast<const float4*>(Wq)
                         : (i < 524288) ? reinterpret_cast<const float4*>(Wk)
                                        : reinterpret_cast<const float4*>(Wv);
      v = src[i & 262143];
      dst = reinterpret_cast<short4*>(Wqkv) + i;
    } else {
      v = reinterpret_cast<const float4*>(Wo)[i - 786432];
      dst = reinterpret_cast<short4*>(Wob) + (i - 786432);
    }
    union { __hip_bfloat16 h[4]; short4 s; } p;
    p.h[0] = __float2bfloat16(v.x);
    p.h[1] = __float2bfloat16(v.y);
    p.h[2] = __float2bfloat16(v.z);
    p.h[3] = __float2bfloat16(v.w);
    *dst = p.s;
  }
}

// ---------------- async global->LDS helper ----------------
__device__ __forceinline__ void gload_lds16(const __hip_bfloat16* g, __hip_bfloat16* l) {
  __builtin_amdgcn_global_load_lds(
      (const __attribute__((address_space(1))) unsigned int*)g,
      (__attribute__((address_space(3))) unsigned int*)l, 16, 0, 0);
}

__device__ __forceinline__ unsigned pk_bf16(float a, float b) {
  union { __hip_bfloat16 h; unsigned short u; } x, y;
  x.h = __float2bfloat16(a);
  y.h = __float2bfloat16(b);
  return (unsigned)x.u | ((unsigned)y.u << 16);
}

// v_permlane32_swap_b32 with correct dataflow (two distinct results).
__device__ __forceinline__ void plswap2(unsigned a, unsigned b, unsigned& x, unsigned& y) {
#if __has_builtin(__builtin_amdgcn_permlane32_swap)
  auto r = __builtin_amdgcn_permlane32_swap(a, b, false, false);
  x = r[0];
  y = r[1];
#else
  unsigned d, s;
  asm volatile("v_mov_b32 %0, %2\n\tv_mov_b32 %1, %3\n\tv_permlane32_swap_b32 %0, %1"
               : "=&v"(d), "=&v"(s)
               : "v"(a), "v"(b));
  x = d;
  y = s;
#endif
}

// ---------------- GEMM: C[M,N] = A[M,K] @ W[N,K]^T + bias ----------------
// 3-buffer stage-1-ahead pipeline (48 KB LDS -> 3 blocks/CU, 12 waves/CU).
// Schedule proof (same as attention R9): STAGE(kt+1)->buf (kt+1)%3 is issued
// only after barrier(kt-1); all waves reached that barrier only after finishing
// compute(kt-2) = last readers of that buffer. vmcnt(4) leaves only stage(kt+1)
// in flight; vmcnt(0) drains on the final iteration.
// R10 lesson: LDS 64 KB (4 buffers) capped occupancy at 2 blocks/CU -> 520 TF.
template <int NB, int OUTMODE>
__global__ __launch_bounds__(256, 4) void k_gemm(
    const __hip_bfloat16* __restrict__ Aq, const __hip_bfloat16* __restrict__ Akv,
    const __hip_bfloat16* __restrict__ Wt,
    const float* __restrict__ b0p, const float* __restrict__ b1p, const float* __restrict__ b2p,
    __hip_bfloat16* __restrict__ Obf, float* __restrict__ Of) {
  const int K = 1024;
  __shared__ __hip_bfloat16 As[3][4096];
  __shared__ __hip_bfloat16 Bs[3][4096];
  const int tid = threadIdx.x;
  const int lane = tid & 63;
  const int w = tid >> 6;
  const int wr = w >> 1, wc = w & 1;
  const int lg = lane >> 4, lr = lane & 15;

  const int bid = blockIdx.x;
  const int xcd = bid & 7, idx = bid >> 3;
  const int m0 = (xcd * 8 + idx / NB) * 128;
  const int n0 = (idx % NB) * 128;

  const int proj = (OUTMODE == 0) ? (n0 >> 10) : 0;
  const __hip_bfloat16* A = (OUTMODE == 0) ? (proj == 0 ? Aq : Akv) : Aq;

  const f32x4 fzero = {0.f, 0.f, 0.f, 0.f};
  f32x4 acc[4][4];
#pragma unroll
  for (int i = 0; i < 4; i++)
#pragma unroll
    for (int j = 0; j < 4; j++) acc[i][j] = fzero;

  const int c0 = w * 2;
  const int srow = lane >> 2;
  const int scol = (lane & 3) * 8;

  auto STAGE = [&](int kt, int buf) {
    const int k0 = kt * 32;
#pragma unroll
    for (int i = 0; i < 2; i++) {
      const int c = c0 + i;
      const int row = c * 16 + srow;
      gload_lds16(A + (size_t)(m0 + row) * K + k0 + scol, As[buf] + c * 512);
      gload_lds16(Wt + (size_t)(n0 + row) * K + k0 + scol, Bs[buf] + c * 512);
    }
  };

  STAGE(0, 0);

  int cur = 0;
  for (int kt = 0; kt < 32; ++kt) {
    if (kt + 1 < 32) {
      const int nb = (cur == 2) ? 0 : cur + 1;
      STAGE(kt + 1, nb);
      asm volatile("s_waitcnt vmcnt(4)" ::: "memory");
    } else {
      asm volatile("s_waitcnt vmcnt(0)" ::: "memory");
    }
    __builtin_amdgcn_s_barrier();

    const int bc = cur;
    short8 af[4], bfr[4];
#pragma unroll
    for (int mi = 0; mi < 4; mi++)
      af[mi] = *(const short8*)(As[bc] + (wr * 64 + mi * 16 + lr) * 32 + lg * 8);
#pragma unroll
    for (int ni = 0; ni < 4; ni++)
      bfr[ni] = *(const short8*)(Bs[bc] + (wc * 64 + ni * 16 + lr) * 32 + lg * 8);
#pragma unroll
    for (int mi = 0; mi < 4; mi++)
#pragma unroll
      for (int ni = 0; ni < 4; ni++)
        acc[mi][ni] = __builtin_amdgcn_mfma_f32_16x16x32_bf16(af[mi], bfr[ni], acc[mi][ni], 0, 0, 0);
    cur = (cur == 2) ? 0 : cur + 1;
  }

  // Q gets 0.125 * LOG2E so scores arrive in exp2 domain.
  const float scale = (OUTMODE == 0 && proj == 0) ? (0.125f * LOG2E) : 1.0f;
  const float* bias = (OUTMODE == 0) ? (proj == 0 ? b0p : (proj == 1 ? b1p : b2p)) : b0p;
  __hip_bfloat16* Ob = (OUTMODE == 0) ? (Obf + (size_t)proj * 8388608) : nullptr;

#pragma unroll
  for (int mi = 0; mi < 4; mi++) {
#pragma unroll
    for (int ni = 0; ni < 4; ni++) {
      const int n = n0 + wc * 64 + ni * 16 + lr;
      const float bn = bias[n & 1023];
#pragma unroll
      for (int r = 0; r < 4; r++) {
        const int m = m0 + wr * 64 + mi * 16 + lg * 4 + r;
        const float v = (acc[mi][ni][r] + bn) * scale;
        if (OUTMODE == 0) {
          const int b = m >> 11, t = m & 2047;
          const int h = (n >> 6) & 15, d = n & 63;
          Ob[(((size_t)(b * 16 + h)) * 2048 + t) * 64 + d] = __float2bfloat16(v);
        } else {
          Of[(size_t)m * 1024 + n] = v;
        }
      }
    }
  }
}

// ---------------- V transpose: [BH, T, 64] -> [BH, 64, T] ----------------
__global__ __launch_bounds__(256) void k_transpose(const __hip_bfloat16* __restrict__ V,
                                                   __hip_bfloat16* __restrict__ Vt) {
  __shared__ __hip_bfloat16 tile[64][72];
  const int bh = blockIdx.y;
  const int t0 = blockIdx.x * 64;
  const int tid = threadIdx.x;
#pragma unroll
  for (int it = 0; it < 2; ++it) {
    const int r = it * 32 + (tid >> 3);
    const int c = (tid & 7) * 8;
    short8 v = *(const short8*)(V + ((size_t)bh * 2048 + t0 + r) * 64 + c);
    *(short8*)(&tile[r][c]) = v;
  }
  __syncthreads();
#pragma unroll
  for (int it = 0; it < 2; ++it) {
    const int d = it * 32 + (tid >> 3);
    const int tt = (tid & 7) * 8;
    __hip_bfloat16 tmp[8];
#pragma unroll
    for (int j = 0; j < 8; j++) tmp[j] = tile[tt + j][d];
    *(short8*)(Vt + ((size_t)bh * 64 + d) * 2048 + t0 + tt) = *(short8*)tmp;
  }
}

// ---------------- banded flash attention: 8-wave, QBLK=256, no-max softmax ----------------
// R11-verified: 3-buffer single-barrier pipeline, loose launch_bounds (allocator free).
__global__ __launch_bounds__(512, 2) void k_attn6(const __hip_bfloat16* __restrict__ Qm,
                                                  const __hip_bfloat16* __restrict__ Km,
                                                  const __hip_bfloat16* __restrict__ Vt,
                                                  __hip_bfloat16* __restrict__ O,
                                                  const int* __restrict__ la_ptr) {
  const int T = 2048;
  __shared__ __hip_bfloat16 Ks[3][4096];  // [key][d], 64x64, XOR-swizzled cols
  __shared__ __hip_bfloat16 Vs[3][4096];  // [d][key]
  const int tid = threadIdx.x;
  const int lane = tid & 63;
  const int w = tid >> 6;          // 0..7
  const int hi = lane >> 5;
  const int l31 = lane & 31;

  // complementary XCD remap, bijective on 512 blocks, longest q-blocks first:
  // XCD x gets qblk {7-x (bh 0..31), x (bh 32..63)} -> tile sums {38,40,...,38}
  const int l = blockIdx.y * 8 + blockIdx.x;
  const int half = l >> 8;
  const int u = l & 255;
  const int xi = u & 7;
  const int yi = u >> 3;
  const int qblk = half ? xi : (7 - xi);
  const int bh = yi + (half << 5);

  const int q0 = qblk * 256;
  const int la = *la_ptr;
  const int qw = q0 + w * 32;
  const int q = qw + l31;

  // Q B-fragments: B[n=q, k=ks*16+hi*8+j]
  short8 qf[4];
  {
    const __hip_bfloat16* qrow = Qm + ((size_t)bh * T + q) * 64;
#pragma unroll
    for (int ks = 0; ks < 4; ks++) qf[ks] = *(const short8*)(qrow + ks * 16 + hi * 8);
  }

  f32x16 acc0, acc1;
#pragma unroll
  for (int r = 0; r < 16; r++) { acc0[r] = 0.f; acc1[r] = 0.f; }
  float lsum = 0.f;

  const int kend_w = min(T, qw + 32 + la);
  const int kend_b = min(T, q0 + 256 + la);
  const int ntiles = (kend_b + 63) >> 6;

  // staging: 512 threads x 16B = one 8KB (64x64) tile per call
  const int srow = tid >> 3;               // 0..63
  const int sc16 = (tid & 7) ^ (srow & 7);
  const __hip_bfloat16* Kg = Km + (size_t)bh * T * 64 + (size_t)srow * 64 + sc16 * 8;
  const __hip_bfloat16* Vg = Vt + (size_t)bh * 64 * T + (size_t)srow * T + sc16 * 8;
  const int kswz = l31 & 7;

  auto STAGEKV = [&](int t, int buf) {
    gload_lds16(Kg + (size_t)(t << 6) * 64, Ks[buf] + w * 512);
    gload_lds16(Vg + (t << 6), Vs[buf] + w * 512);
  };

  auto QK = [&](const __hip_bfloat16* Ksc, int kt2) {
    const int krow = kt2 * 32 + l31;
    f32x16 s;
#pragma unroll
    for (int r = 0; r < 16; r++) s[r] = 0.f;
    __builtin_amdgcn_s_setprio(1);
#pragma unroll
    for (int ks = 0; ks < 4; ks++) {
      short8 kf = *(const short8*)((const char*)Ksc + krow * 128 +
                                   ((((ks << 1) | hi)) ^ kswz) * 16);
      s = __builtin_amdgcn_mfma_f32_32x32x16_bf16(kf, qf[ks], s, 0, 0, 0);
    }
    __builtin_amdgcn_s_setprio(0);
    return s;
  };

  auto SMPV = [&](f32x16& s, int kb32, int kt2, const __hip_bfloat16* Vsc) {
    if (kb32 + 31 > qw + la) {
      const int thr = q + la - kb32;
#pragma unroll
      for (int r = 0; r < 16; r++) {
        const int crow = (r & 3) + ((r >> 2) << 3) + (hi << 2);
        if (crow > thr) s[r] = -1e30f;
      }
    }
    // no-max softmax: P = exp2(S), exact by shift-invariance (|S| small)
    float e[16];
#pragma unroll
    for (int i = 0; i < 16; i++) e[i] = exp2f(s[i]);
    float p01 = (e[0] + e[1]) + (e[2] + e[3]);
    float p23 = (e[4] + e[5]) + (e[6] + e[7]);
    float p45 = (e[8] + e[9]) + (e[10] + e[11]);
    float p67 = (e[12] + e[13]) + (e[14] + e[15]);
    lsum += (p01 + p23) + (p45 + p67);
    unsigned W[8];
#pragma unroll
    for (int i = 0; i < 8; i++) W[i] = pk_bf16(e[2 * i], e[2 * i + 1]);

    int4 A0, A1;
    {
      unsigned x0, z0, y0, w0, x1, z1, y1, w1;
      plswap2(W[0], W[2], x0, z0);
      plswap2(W[1], W[3], y0, w0);
      plswap2(W[4], W[6], x1, z1);
      plswap2(W[5], W[7], y1, w1);
      A0.x = (int)x0; A0.y = (int)y0; A0.z = (int)z0; A0.w = (int)w0;
      A1.x = (int)x1; A1.y = (int)y1; A1.z = (int)z1; A1.w = (int)w1;
    }

    __builtin_amdgcn_s_setprio(1);
#pragma unroll
    for (int ks2 = 0; ks2 < 2; ks2++) {
      union { int4 i; short8 s8; } pa;
      pa.i = ks2 ? A1 : A0;
      const int ksg = kt2 * 2 + ks2;
      const int col16 = ((ksg << 1) | hi);
      short8 vf0 = *(const short8*)((const char*)Vsc + l31 * 128 + ((col16 ^ kswz)) * 16);
      short8 vf1 = *(const short8*)((const char*)Vsc + (32 + l31) * 128 + ((col16 ^ kswz)) * 16);
      acc0 = __builtin_amdgcn_mfma_f32_32x32x16_bf16(vf0, pa.s8, acc0, 0, 0, 0);
      acc1 = __builtin_amdgcn_mfma_f32_32x32x16_bf16(vf1, pa.s8, acc1, 0, 0, 0);
    }
    __builtin_amdgcn_s_setprio(0);
  };

  // prologue: stage tile 0 into buf 0
  STAGEKV(0, 0);

  int cur = 0, nxt = 1;
  for (int kt = 0; kt < ntiles; ++kt) {
    const int kbase = kt << 6;
    if (kt + 1 < ntiles) {
      STAGEKV(kt + 1, nxt);
      asm volatile("s_waitcnt vmcnt(2)" ::: "memory");
    } else {
      asm volatile("s_waitcnt vmcnt(0)" ::: "memory");
    }
    __builtin_amdgcn_s_barrier();

    if (kbase < kend_w) {
      const __hip_bfloat16* Ksc = Ks[cur];
      const __hip_bfloat16* Vsc = Vs[cur];
      const bool d1 = (kbase + 32) < kend_w;
      f32x16 sA = QK(Ksc, 0);
      f32x16 sB;
      if (d1) sB = QK(Ksc, 1);
      SMPV(sA, kbase, 0, Vsc);
      if (d1) SMPV(sB, kbase + 32, 1, Vsc);
    }
    cur = nxt;
    nxt = (nxt == 2) ? 0 : nxt + 1;
  }

  {
    unsigned r0, r1;
    plswap2(__float_as_uint(lsum), __float_as_uint(lsum), r0, r1);
    lsum = __uint_as_float(r0) + __uint_as_float(r1);
  }
  const float rinv = 1.f / lsum;
  const int b = bh >> 4, h = bh & 15;
  __hip_bfloat16* orow = O + ((size_t)(b * T + q)) * 1024 + h * 64;
#pragma unroll
  for (int rq = 0; rq < 4; rq++) {
    const int d0 = rq * 8 + hi * 4;
    union { __hip_bfloat16 h4[4]; short4 s4; } o;
#pragma unroll
    for (int j = 0; j < 4; j++) o.h4[j] = __float2bfloat16(acc0[rq * 4 + j] * rinv);
    *(short4*)(orow + d0) = o.s4;
  }
#pragma unroll
  for (int rq = 0; rq < 4; rq++) {
    const int d0 = rq * 8 + hi * 4 + 32;
    union { __hip_bfloat16 h4[4]; short4 s4; } o;
#pragma unroll
    for (int j = 0; j < 4; j++) o.h4[j] = __float2bfloat16(acc1[rq * 4 + j] * rinv);
    *(short4*)(orow + d0) = o.s4;
  }
}

// ---------------- launch ----------------
extern "C" void kernel_launch(void* const* d_in, const int* in_sizes, int n_in,
                              void* d_out, int out_size, void* d_ws, size_t ws_size,
                              hipStream_t stream) {
  const float* q_in = (const float*)d_in[0];
  const float* kv_in = (const float*)d_in[1];
  const float* Wq = (const float*)d_in[2];
  const float* bq = (const float*)d_in[3];
  const float* Wk = (const float*)d_in[4];
  const float* bk = (const float*)d_in[5];
  const float* Wv = (const float*)d_in[6];
  const float* bv = (const float*)d_in[7];
  const float* Wo = (const float*)d_in[8];
  const float* bo = (const float*)d_in[9];
  const int* la = (const int*)d_in[10];

  char* ws = (char*)d_ws;
  const size_t SZX = (size_t)8192 * 1024 * 2;  // 16 MiB
  const size_t SZW = (size_t)1024 * 1024 * 2;  // 2 MiB
  __hip_bfloat16* Xq = (__hip_bfloat16*)(ws);                 // +Xkv contiguous
  __hip_bfloat16* Xkv = (__hip_bfloat16*)(ws + SZX);
  __hip_bfloat16* Wqkv = (__hip_bfloat16*)(ws + 2 * SZX);     // 6 MiB
  __hip_bfloat16* Wob = (__hip_bfloat16*)(ws + 2 * SZX + 3 * SZW);
  __hip_bfloat16* Qb = (__hip_bfloat16*)(ws + 2 * SZX + 4 * SZW);  // Qb|Kb|Vb contiguous
  __hip_bfloat16* Kb = (__hip_bfloat16*)(ws + 3 * SZX + 4 * SZW);
  __hip_bfloat16* Vb = (__hip_bfloat16*)(ws + 4 * SZX + 4 * SZW);
  __hip_bfloat16* Vtb = (__hip_bfloat16*)(ws);        // alias Xq (free after QKV GEMM)
  __hip_bfloat16* AOb = (__hip_bfloat16*)(ws + SZX);  // alias Xkv (free after QKV GEMM)

  k_cvtX<<<4096, 256, 0, stream>>>(q_in, kv_in, Xq);
  k_cvtW<<<2048, 256, 0, stream>>>(Wq, Wk, Wv, Wo, Wqkv, Wob);

  // fused QKV projection: 64 m-blocks x 24 n-blocks
  k_gemm<24, 0><<<1536, 256, 0, stream>>>(Xq, Xkv, Wqkv, bq, bk, bv, Qb, nullptr);
  k_transpose<<<dim3(32, 64), 256, 0, stream>>>(Vb, Vtb);
  k_attn6<<<dim3(8, 64), 512, 0, stream>>>(Qb, Kb, Vtb, AOb, la);
  // output projection: 64 x 8 blocks, f32 out
  k_gemm<8, 1><<<512, 256, 0, stream>>>(AOb, AOb, Wob, bo, bo, bo, nullptr, (float*)d_out);

  (void)Kb;
}